// Round 5
// baseline (206.852 us; speedup 1.0000x reference)
//
#include <hip/hip_runtime.h>

// LocalizationVAE spot rendering: B=8192 images 64x64, 64 spots each.
// R4 -> R5: persistent single-wave blocks (grid-stride over images).
//   Evidence: BW pinned ~1.5 TB/s invariant to VALU load, occupancy, nt flag.
//   Theory: per-block lifecycle latency (launch + cold z + store drain +
//   LDS realloc) is the serializer at ~6.5 concurrent blocks/CU. Persistent
//   blocks reuse LDS, keep stores streaming across images, and raise
//   concurrency to the LDS cap (10 blocks/CU, 2560 blocks).

constexpr int NXc = 64;
constexpr int NYc = 64;
constexpr int IMG = NXc * NYc;             // 4096 floats = 16 KiB
constexpr int PATCH_HW = 3;
constexpr int PP = 6;
constexpr float I0c = 1000.0f;
constexpr float INV_ALPHA = 0.76859415f;   // 1/(sqrt(2)*0.92)
constexpr int GRID = 2560;                 // 256 CU x 10 blocks (16 KiB LDS cap)

typedef float f32x4 __attribute__((ext_vector_type(4)));

// Abramowitz & Stegun 7.1.26, |error| <= 1.5e-7 over all x
__device__ __forceinline__ float fast_erf(float x) {
    const float ax = __builtin_fabsf(x);
    const float t  = __builtin_amdgcn_rcpf(__builtin_fmaf(0.3275911f, ax, 1.0f));
    float y = __builtin_fmaf(1.061405429f, t, -1.453152027f);
    y = __builtin_fmaf(y, t, 1.421413741f);
    y = __builtin_fmaf(y, t, -0.284496736f);
    y = __builtin_fmaf(y, t, 0.254829592f);
    y = y * t;
    const float e = __expf(-ax * ax);
    const float r = __builtin_fmaf(-y, e, 1.0f);
    return __builtin_copysignf(r, x);
}

__global__ __launch_bounds__(64) void loc_spots_kernel(
        const float* __restrict__ z, float* __restrict__ out, int B) {
    __shared__ float mu[IMG];              // 16 KiB, private to this wave
    const int l = threadIdx.x;             // lane == spot index
    f32x4* mu4 = reinterpret_cast<f32x4*>(mu);

    for (int b = blockIdx.x; b < B; b += GRID) {
        // load this image's spots early (L2/L3-warm after first pass)
        const float x0 = z[b * 128 + l];
        const float y0 = z[b * 128 + 64 + l];

        // zero LDS image
#pragma unroll
        for (int i = 0; i < 16; ++i)
            mu4[l + i * 64] = (f32x4)(0.f);
        __syncthreads();

        const int px = (int)rintf(x0) - PATCH_HW;   // jnp.round == rintf
        const int py = (int)rintf(y0) - PATCH_HW;
        const bool valid = (px >= 0) && (px < NXc - PP) &&
                           (py >= 0) && (py < NYc - PP);

        if (valid) {
            const float x0p = x0 - (float)px;
            const float y0p = y0 - (float)py;

            float bx[PP + 1], by[PP + 1];
#pragma unroll
            for (int k = 0; k <= PP; ++k) {
                bx[k] = fast_erf(((float)k - 0.5f - x0p) * INV_ALPHA);
                by[k] = fast_erf(((float)k - 0.5f - y0p) * INV_ALPHA);
            }
            float lxs[PP], ly[PP];
#pragma unroll
            for (int t = 0; t < PP; ++t) {
                lxs[t] = (0.5f * I0c) * (bx[t + 1] - bx[t]);
                ly[t]  = 0.5f * (by[t + 1] - by[t]);
            }

            const int base = px * NYc + py;
#pragma unroll
            for (int i = 0; i < PP; ++i)
#pragma unroll
                for (int j = 0; j < PP; ++j)
                    atomicAdd(&mu[base + i * NYc + j], lxs[i] * ly[j]);
        }
        __syncthreads();

        // writeout: ds_read image into regs, nt stores stream to HBM.
        // VGPR reclaim (vmcnt) only needs store-data-read, not HBM ack,
        // so stores of image b overlap compute of image b+GRID.
        f32x4* out4 = reinterpret_cast<f32x4*>(out + (size_t)b * IMG);
#pragma unroll
        for (int c = 0; c < 4; ++c) {
            f32x4 v0 = mu4[l + (c * 4 + 0) * 64];
            f32x4 v1 = mu4[l + (c * 4 + 1) * 64];
            f32x4 v2 = mu4[l + (c * 4 + 2) * 64];
            f32x4 v3 = mu4[l + (c * 4 + 3) * 64];
            __builtin_nontemporal_store(v0, &out4[l + (c * 4 + 0) * 64]);
            __builtin_nontemporal_store(v1, &out4[l + (c * 4 + 1) * 64]);
            __builtin_nontemporal_store(v2, &out4[l + (c * 4 + 2) * 64]);
            __builtin_nontemporal_store(v3, &out4[l + (c * 4 + 3) * 64]);
        }
        __syncthreads();   // LDS rezero next iter must not pass ds_reads
    }
}

extern "C" void kernel_launch(void* const* d_in, const int* in_sizes, int n_in,
                              void* d_out, int out_size, void* d_ws, size_t ws_size,
                              hipStream_t stream) {
    const float* z = (const float*)d_in[0];
    float* out = (float*)d_out;
    const int B = in_sizes[0] / 128;       // 8192 images
    loc_spots_kernel<<<GRID, 64, 0, stream>>>(z, out, B);
}

// Round 6
// 195.307 us; speedup vs baseline: 1.0591x; 1.0591x over previous
//
#include <hip/hip_runtime.h>

// LocalizationVAE spot rendering: B=8192 images 64x64, 64 spots each.
// R5 -> R6: revert persistence (it cost 5% via 4-vs-3-image tail imbalance).
// Final structure = R2: one 64-thread wave per image, LDS-accumulated spots,
// coalesced float4 writeout.
//
// Ceiling analysis (R1-R5): write BW pinned at 1.42-1.50 TB/s invariant to
// VALU load (37->4.5%), occupancy (76->18%), nt vs cached stores, and
// persistent vs per-image blocks. Harness's own hipMemsetAsync re-poison
// also runs at ~1.35 TB/s (stable ~105us for ~140MB every round). So
// ~1.45-1.5 TB/s is this device's pure-write ceiling; floor = 131MB / 1.5
// = ~87us. This kernel: ~91us = within ~5% of the write roofline.

constexpr int NXc = 64;
constexpr int NYc = 64;
constexpr int IMG = NXc * NYc;             // 4096 floats = 16 KiB
constexpr int PATCH_HW = 3;
constexpr int PP = 6;
constexpr float I0c = 1000.0f;
constexpr float INV_ALPHA = 0.76859415f;   // 1/(sqrt(2)*0.92)

typedef float f32x4 __attribute__((ext_vector_type(4)));

// Abramowitz & Stegun 7.1.26, |error| <= 1.5e-7 over all x
__device__ __forceinline__ float fast_erf(float x) {
    const float ax = __builtin_fabsf(x);
    const float t  = __builtin_amdgcn_rcpf(__builtin_fmaf(0.3275911f, ax, 1.0f));
    float y = __builtin_fmaf(1.061405429f, t, -1.453152027f);
    y = __builtin_fmaf(y, t, 1.421413741f);
    y = __builtin_fmaf(y, t, -0.284496736f);
    y = __builtin_fmaf(y, t, 0.254829592f);
    y = y * t;
    const float e = __expf(-ax * ax);
    const float r = __builtin_fmaf(-y, e, 1.0f);
    return __builtin_copysignf(r, x);
}

__global__ __launch_bounds__(64) void loc_spots_kernel(
        const float* __restrict__ z, float* __restrict__ out) {
    __shared__ float mu[IMG];              // 16 KiB, private to this wave
    const int b = blockIdx.x;
    const int l = threadIdx.x;             // lane == spot index

    // issue spot loads early (HBM latency overlaps LDS zeroing)
    const float x0 = z[b * 128 + l];
    const float y0 = z[b * 128 + 64 + l];

    // zero LDS image
    f32x4* mu4 = reinterpret_cast<f32x4*>(mu);
#pragma unroll
    for (int i = 0; i < 16; ++i)
        mu4[l + i * 64] = (f32x4)(0.f);
    __syncthreads();

    const int px = (int)rintf(x0) - PATCH_HW;   // jnp.round == rintf
    const int py = (int)rintf(y0) - PATCH_HW;
    const bool valid = (px >= 0) && (px < NXc - PP) &&
                       (py >= 0) && (py < NYc - PP);

    if (valid) {
        const float x0p = x0 - (float)px;
        const float y0p = y0 - (float)py;

        float bx[PP + 1], by[PP + 1];
#pragma unroll
        for (int k = 0; k <= PP; ++k) {
            bx[k] = fast_erf(((float)k - 0.5f - x0p) * INV_ALPHA);
            by[k] = fast_erf(((float)k - 0.5f - y0p) * INV_ALPHA);
        }
        float lxs[PP], ly[PP];
#pragma unroll
        for (int t = 0; t < PP; ++t) {
            lxs[t] = (0.5f * I0c) * (bx[t + 1] - bx[t]);   // premultiply I0
            ly[t]  = 0.5f * (by[t + 1] - by[t]);
        }

        const int base = px * NYc + py;
#pragma unroll
        for (int i = 0; i < PP; ++i)
#pragma unroll
            for (int j = 0; j < PP; ++j)
                atomicAdd(&mu[base + i * NYc + j], lxs[i] * ly[j]);
    }
    __syncthreads();

    // coalesced writeout: 16 x (ds_read_b128 + global_store_dwordx4)
    f32x4* out4 = reinterpret_cast<f32x4*>(out + (size_t)b * IMG);
#pragma unroll
    for (int i = 0; i < 16; ++i)
        out4[l + i * 64] = mu4[l + i * 64];
}

extern "C" void kernel_launch(void* const* d_in, const int* in_sizes, int n_in,
                              void* d_out, int out_size, void* d_ws, size_t ws_size,
                              hipStream_t stream) {
    const float* z = (const float*)d_in[0];
    float* out = (float*)d_out;
    const int B = in_sizes[0] / 128;       // 8192 images
    loc_spots_kernel<<<B, 64, 0, stream>>>(z, out);
}